// Round 2
// baseline (598.017 us; speedup 1.0000x reference)
//
#include <hip/hip_runtime.h>
#include <math.h>

#define Bdim 32
#define Cdim 256
#define Hdim 64
#define Wdim 64
#define HW   (Hdim * Wdim)          // 4096
#define KS   5
#define HID  64
#define E_LAMBDA 1e-4f

typedef float vfloat4 __attribute__((ext_vector_type(4)));

// fast sigmoid: native v_exp_f32 + v_rcp_f32 (abs err ~1e-6, threshold 8e-2)
__device__ __forceinline__ float sigmoidf(float v) {
    return __builtin_amdgcn_rcpf(1.0f + __expf(-v));
}

// ---------------- Kernel 1: per-channel stats + SimAM sum + last-block gate/MLP
// One block per (b,c) channel. 256 threads x 16 floats = 4096 elements held
// in registers; one HBM read of x (also warms L3 for kernel 2).
// After publishing stats, each block takes a ticket on counter[b]; the LAST
// block of batch b (ticket 255) computes the ECA conv + fusion MLP for that
// batch inline. No spinning, no co-residency assumption -> deadlock-free.
__global__ __launch_bounds__(256) void stats_gate_kernel(
        const float* __restrict__ x,
        const float* __restrict__ conv_w,
        const float* __restrict__ w1,
        const float* __restrict__ w2,
        float* __restrict__ mean_out,
        float* __restrict__ inv_out,      // 0.25/(var+eps)
        float* __restrict__ ssum_out,
        float* __restrict__ gate_out,
        float* __restrict__ alpha_out,
        int*   __restrict__ counter) {    // [Bdim], zeroed by memset node
    const int bc = blockIdx.x;
    const int b  = bc >> 8;
    const vfloat4* __restrict__ x4 = (const vfloat4*)(x + (size_t)bc * HW);
    const int t = threadIdx.x;
    const int lane = t & 63;
    const int wid  = t >> 6;

    __shared__ float red[8];
    __shared__ float bcast[2];
    __shared__ int   slast;

    vfloat4 v[4];
    float sum = 0.0f, sq = 0.0f;
#pragma unroll
    for (int i = 0; i < 4; ++i) {
        v[i] = x4[t + 256 * i];
        sum += v[i].x + v[i].y + v[i].z + v[i].w;
        sq  += v[i].x * v[i].x + v[i].y * v[i].y
             + v[i].z * v[i].z + v[i].w * v[i].w;
    }
#pragma unroll
    for (int off = 32; off > 0; off >>= 1) {
        sum += __shfl_down(sum, off);
        sq  += __shfl_down(sq, off);
    }
    if (lane == 0) { red[wid] = sum; red[4 + wid] = sq; }
    __syncthreads();
    if (t == 0) {
        const float ts = red[0] + red[1] + red[2] + red[3];
        const float tq = red[4] + red[5] + red[6] + red[7];
        const float mn  = ts * (1.0f / HW);
        const float var = (tq - ts * ts * (1.0f / HW)) * (1.0f / (HW - 1));
        mean_out[bc] = mn;
        inv_out[bc]  = 0.25f / (var + E_LAMBDA);
        bcast[0] = mn;
        bcast[1] = 0.25f / (var + E_LAMBDA);
    }
    __syncthreads();
    const float mn  = bcast[0];
    const float inv = bcast[1];

    // SimAM: sum over channel of x * sigmoid(d^2/(4(var+eps)) + 0.5)
    float p = 0.0f;
#pragma unroll
    for (int i = 0; i < 4; ++i) {
        float d;
        d = v[i].x - mn; p += v[i].x * sigmoidf(d * d * inv + 0.5f);
        d = v[i].y - mn; p += v[i].y * sigmoidf(d * d * inv + 0.5f);
        d = v[i].z - mn; p += v[i].z * sigmoidf(d * d * inv + 0.5f);
        d = v[i].w - mn; p += v[i].w * sigmoidf(d * d * inv + 0.5f);
    }
#pragma unroll
    for (int off = 32; off > 0; off >>= 1) p += __shfl_down(p, off);
    if (lane == 0) red[wid] = p;
    __syncthreads();

    // ---- ticket: last block of this batch computes the gate + MLP ----------
    if (t == 0) {
        ssum_out[bc] = red[0] + red[1] + red[2] + red[3];
        __threadfence();                         // release stats device-wide
        const int old = atomicAdd(&counter[b], 1);
        slast = (old == Cdim - 1);
    }
    __syncthreads();
    if (!slast) return;

    __threadfence();                             // acquire: discard stale lines

    __shared__ float sm[Cdim];
    __shared__ float sgap[Cdim];
    __shared__ float shid[HID];

    const float mb = mean_out[b * Cdim + t];
    const float sb = ssum_out[b * Cdim + t];
    sm[t] = mb;
    __syncthreads();

    // ECA: cross-correlation over channel dim, zero-padded by 2
    float acc = 0.0f;
#pragma unroll
    for (int k = 0; k < KS; ++k) {
        const int cc = t + k - (KS - 1) / 2;
        const float mv = (cc >= 0 && cc < Cdim) ? sm[cc] : 0.0f;
        acc += conv_w[k] * mv;
    }
    const float gate = sigmoidf(acc);
    gate_out[b * Cdim + t] = gate;
    // gap = mean(x_eca + x_simam) = gate*mean + ssum/HW
    sgap[t] = gate * mb + sb * (1.0f / HW);
    __syncthreads();

    if (t < HID) {
        const vfloat4* __restrict__ w14 = (const vfloat4*)(w1 + t * Cdim);
        const vfloat4* __restrict__ g4  = (const vfloat4*)sgap;
        float h = 0.0f;
#pragma unroll
        for (int i = 0; i < Cdim / 4; ++i) {
            const vfloat4 wv = w14[i];
            const vfloat4 gv = g4[i];
            h += wv.x * gv.x + wv.y * gv.y + wv.z * gv.z + wv.w * gv.w;
        }
        shid[t] = fmaxf(h, 0.0f);
    }
    __syncthreads();

    {
        const vfloat4* __restrict__ w24 = (const vfloat4*)(w2 + t * HID);
        const vfloat4* __restrict__ h4  = (const vfloat4*)shid;
        float a = 0.0f;
#pragma unroll
        for (int j = 0; j < HID / 4; ++j) {
            const vfloat4 wv = w24[j];
            const vfloat4 hv = h4[j];
            a += wv.x * hv.x + wv.y * hv.y + wv.z * hv.z + wv.w * hv.w;
        }
        alpha_out[b * Cdim + t] = sigmoidf(a);
    }
}

// ---------------- Kernel 2: final elementwise blend -----------------------
// out = x * (alpha * s + (1-alpha) * gate),  s = sigmoid(d^2*inv + 0.5)
// x re-read should hit L3 (warmed by kernel 1); out uses NON-TEMPORAL stores
// so the 128 MiB output stream does not evict x from the 256 MiB L3.
__global__ __launch_bounds__(256) void final_kernel(
        const float* __restrict__ x,
        const float* __restrict__ mean_c,
        const float* __restrict__ inv_c,
        const float* __restrict__ eca,
        const float* __restrict__ alpha,
        float* __restrict__ out) {
    const int bc = blockIdx.x;
    const float mn  = mean_c[bc];
    const float inv = inv_c[bc];
    const float g   = eca[bc];
    const float a   = alpha[bc];
    const float one_minus_a_g = (1.0f - a) * g;

    const vfloat4* __restrict__ x4 = (const vfloat4*)(x + (size_t)bc * HW);
    vfloat4* __restrict__ o4 = (vfloat4*)(out + (size_t)bc * HW);
    const int t = threadIdx.x;

#pragma unroll
    for (int i = 0; i < 4; ++i) {
        const vfloat4 v = x4[t + 256 * i];
        vfloat4 r;
        float d;
        d = v.x - mn; r.x = v.x * (a * sigmoidf(d * d * inv + 0.5f) + one_minus_a_g);
        d = v.y - mn; r.y = v.y * (a * sigmoidf(d * d * inv + 0.5f) + one_minus_a_g);
        d = v.z - mn; r.z = v.z * (a * sigmoidf(d * d * inv + 0.5f) + one_minus_a_g);
        d = v.w - mn; r.w = v.w * (a * sigmoidf(d * d * inv + 0.5f) + one_minus_a_g);
        __builtin_nontemporal_store(r, &o4[t + 256 * i]);
    }
}

extern "C" void kernel_launch(void* const* d_in, const int* in_sizes, int n_in,
                              void* d_out, int out_size, void* d_ws, size_t ws_size,
                              hipStream_t stream) {
    const float* x      = (const float*)d_in[0];
    const float* conv_w = (const float*)d_in[1];
    const float* w1     = (const float*)d_in[2];
    const float* w2     = (const float*)d_in[3];
    float* out = (float*)d_out;

    const int BC = Bdim * Cdim;   // 8192
    float* mean_c = (float*)d_ws;            // [BC]
    float* inv_c  = mean_c + BC;             // [BC]
    float* ssum   = inv_c + BC;              // [BC]
    float* eca    = ssum + BC;               // [BC]
    float* alpha  = eca + BC;                // [BC]
    int*   cnt    = (int*)(alpha + BC);      // [Bdim]

    // counters must be zero each replay; memset node is graph-capturable
    hipMemsetAsync(cnt, 0, Bdim * sizeof(int), stream);

    stats_gate_kernel<<<BC, 256, 0, stream>>>(x, conv_w, w1, w2,
                                              mean_c, inv_c, ssum, eca, alpha, cnt);
    final_kernel<<<BC, 256, 0, stream>>>(x, mean_c, inv_c, eca, alpha, out);
}

// Round 3
// 311.603 us; speedup vs baseline: 1.9192x; 1.9192x over previous
//
#include <hip/hip_runtime.h>
#include <math.h>

#define Bdim 32
#define Cdim 256
#define Hdim 64
#define Wdim 64
#define HW   (Hdim * Wdim)          // 4096
#define KS   5
#define HID  64
#define E_LAMBDA 1e-4f

typedef float vfloat4 __attribute__((ext_vector_type(4)));

// fast sigmoid: native v_exp_f32 + v_rcp_f32 (abs err ~1e-6, threshold 8e-2)
__device__ __forceinline__ float sigmoidf(float v) {
    return __builtin_amdgcn_rcpf(1.0f + __expf(-v));
}

// ---------------- Kernel 1: per-channel stats + SimAM sum + last-block gate/MLP
//
// One block per (b,c) channel; x held in registers (one HBM read, warms L3
// for kernel 2). Cross-block handoff of {mean, ssum} uses SCOPED RELAXED
// ATOMICS only (per-instruction sc0/sc1 cache-bypass bits) — NO __threadfence,
// NO buffer_wbl2/buffer_inv. Round-2 lesson: agent-scope fences per block
// invalidate L1/L2 device-wide and collapse the kernel to 162 GB/s.
//
// Protocol: t0 scoped-stores mean & ssum -> s_waitcnt vmcnt(0) (plain wait,
// stores are then AT the coherent point) -> relaxed ticket atomicAdd. The
// block drawing ticket 255 for batch b reads all 256 channels' stats with
// scoped loads (bypass stale caches) and computes ECA conv + fusion MLP.
// No spinning, no co-residency assumption, dispatch-order independent.
__global__ __launch_bounds__(256) void stats_gate_kernel(
        const float* __restrict__ x,
        const float* __restrict__ conv_w,
        const float* __restrict__ w1,
        const float* __restrict__ w2,
        float* __restrict__ mean_out,
        float* __restrict__ inv_out,      // 0.25/(var+eps), consumed by kernel 2
        float* __restrict__ ssum_out,
        float* __restrict__ gate_out,
        float* __restrict__ alpha_out,
        int*   __restrict__ counter) {    // [Bdim], zeroed by memset node
    const int bc = blockIdx.x;
    const int b  = bc >> 8;
    const vfloat4* __restrict__ x4 = (const vfloat4*)(x + (size_t)bc * HW);
    const int t = threadIdx.x;
    const int lane = t & 63;
    const int wid  = t >> 6;

    __shared__ float red[8];
    __shared__ float bcast[2];
    __shared__ int   slast;

    vfloat4 v[4];
    float sum = 0.0f, sq = 0.0f;
#pragma unroll
    for (int i = 0; i < 4; ++i) {
        v[i] = x4[t + 256 * i];
        sum += v[i].x + v[i].y + v[i].z + v[i].w;
        sq  += v[i].x * v[i].x + v[i].y * v[i].y
             + v[i].z * v[i].z + v[i].w * v[i].w;
    }
#pragma unroll
    for (int off = 32; off > 0; off >>= 1) {
        sum += __shfl_down(sum, off);
        sq  += __shfl_down(sq, off);
    }
    if (lane == 0) { red[wid] = sum; red[4 + wid] = sq; }
    __syncthreads();
    if (t == 0) {
        const float ts = red[0] + red[1] + red[2] + red[3];
        const float tq = red[4] + red[5] + red[6] + red[7];
        const float mn  = ts * (1.0f / HW);
        const float var = (tq - ts * ts * (1.0f / HW)) * (1.0f / (HW - 1));
        const float iv  = 0.25f / (var + E_LAMBDA);
        // scoped store: lands at device-coherent point, no cache maintenance
        __hip_atomic_store(&mean_out[bc], mn, __ATOMIC_RELAXED,
                           __HIP_MEMORY_SCOPE_AGENT);
        inv_out[bc] = iv;                 // consumed only after kernel boundary
        bcast[0] = mn;
        bcast[1] = iv;
    }
    __syncthreads();
    const float mn  = bcast[0];
    const float inv = bcast[1];

    // SimAM: sum over channel of x * sigmoid(d^2/(4(var+eps)) + 0.5)
    float p = 0.0f;
#pragma unroll
    for (int i = 0; i < 4; ++i) {
        float d;
        d = v[i].x - mn; p += v[i].x * sigmoidf(d * d * inv + 0.5f);
        d = v[i].y - mn; p += v[i].y * sigmoidf(d * d * inv + 0.5f);
        d = v[i].z - mn; p += v[i].z * sigmoidf(d * d * inv + 0.5f);
        d = v[i].w - mn; p += v[i].w * sigmoidf(d * d * inv + 0.5f);
    }
#pragma unroll
    for (int off = 32; off > 0; off >>= 1) p += __shfl_down(p, off);
    if (lane == 0) red[wid] = p;
    __syncthreads();

    // ---- ticket: last block of this batch computes the gate + MLP ----------
    if (t == 0) {
        __hip_atomic_store(&ssum_out[bc], red[0] + red[1] + red[2] + red[3],
                           __ATOMIC_RELAXED, __HIP_MEMORY_SCOPE_AGENT);
        // plain drain: scoped stores are complete at the coherent point after
        // this; NOT a cache-maintenance fence.
        asm volatile("s_waitcnt vmcnt(0)" ::: "memory");
        const int old = __hip_atomic_fetch_add(&counter[b], 1, __ATOMIC_RELAXED,
                                               __HIP_MEMORY_SCOPE_AGENT);
        slast = (old == Cdim - 1);
    }
    __syncthreads();
    if (!slast) return;

    __shared__ float sm[Cdim];
    __shared__ float sgap[Cdim];
    __shared__ float shid[HID];

    // scoped loads: read at the coherent point, bypass stale L1/L2
    const float mb = __hip_atomic_load(&mean_out[b * Cdim + t],
                                       __ATOMIC_RELAXED, __HIP_MEMORY_SCOPE_AGENT);
    const float sb = __hip_atomic_load(&ssum_out[b * Cdim + t],
                                       __ATOMIC_RELAXED, __HIP_MEMORY_SCOPE_AGENT);
    sm[t] = mb;
    __syncthreads();

    // ECA: cross-correlation over channel dim, zero-padded by 2
    float acc = 0.0f;
#pragma unroll
    for (int k = 0; k < KS; ++k) {
        const int cc = t + k - (KS - 1) / 2;
        const float mv = (cc >= 0 && cc < Cdim) ? sm[cc] : 0.0f;
        acc += conv_w[k] * mv;
    }
    const float gate = sigmoidf(acc);
    gate_out[b * Cdim + t] = gate;        // kernel boundary makes this visible
    // gap = mean(x_eca + x_simam) = gate*mean + ssum/HW
    sgap[t] = gate * mb + sb * (1.0f / HW);
    __syncthreads();

    if (t < HID) {
        const vfloat4* __restrict__ w14 = (const vfloat4*)(w1 + t * Cdim);
        const vfloat4* __restrict__ g4  = (const vfloat4*)sgap;
        float h = 0.0f;
#pragma unroll
        for (int i = 0; i < Cdim / 4; ++i) {
            const vfloat4 wv = w14[i];
            const vfloat4 gv = g4[i];
            h += wv.x * gv.x + wv.y * gv.y + wv.z * gv.z + wv.w * gv.w;
        }
        shid[t] = fmaxf(h, 0.0f);
    }
    __syncthreads();

    {
        const vfloat4* __restrict__ w24 = (const vfloat4*)(w2 + t * HID);
        const vfloat4* __restrict__ h4  = (const vfloat4*)shid;
        float a = 0.0f;
#pragma unroll
        for (int j = 0; j < HID / 4; ++j) {
            const vfloat4 wv = w24[j];
            const vfloat4 hv = h4[j];
            a += wv.x * hv.x + wv.y * hv.y + wv.z * hv.z + wv.w * hv.w;
        }
        alpha_out[b * Cdim + t] = sigmoidf(a);
    }
}

// ---------------- Kernel 2: final elementwise blend -----------------------
// out = x * (alpha * s + (1-alpha) * gate),  s = sigmoid(d^2*inv + 0.5)
// x re-read should hit L3 (warmed by kernel 1); out uses NON-TEMPORAL stores
// so the 128 MiB output stream does not evict x from the 256 MiB L3.
__global__ __launch_bounds__(256) void final_kernel(
        const float* __restrict__ x,
        const float* __restrict__ mean_c,
        const float* __restrict__ inv_c,
        const float* __restrict__ eca,
        const float* __restrict__ alpha,
        float* __restrict__ out) {
    const int bc = blockIdx.x;
    const float mn  = mean_c[bc];
    const float inv = inv_c[bc];
    const float g   = eca[bc];
    const float a   = alpha[bc];
    const float one_minus_a_g = (1.0f - a) * g;

    const vfloat4* __restrict__ x4 = (const vfloat4*)(x + (size_t)bc * HW);
    vfloat4* __restrict__ o4 = (vfloat4*)(out + (size_t)bc * HW);
    const int t = threadIdx.x;

    // load all 16 floats first (independent addresses -> deep in flight)
    vfloat4 v[4];
#pragma unroll
    for (int i = 0; i < 4; ++i) v[i] = x4[t + 256 * i];

#pragma unroll
    for (int i = 0; i < 4; ++i) {
        vfloat4 r;
        float d;
        d = v[i].x - mn; r.x = v[i].x * (a * sigmoidf(d * d * inv + 0.5f) + one_minus_a_g);
        d = v[i].y - mn; r.y = v[i].y * (a * sigmoidf(d * d * inv + 0.5f) + one_minus_a_g);
        d = v[i].z - mn; r.z = v[i].z * (a * sigmoidf(d * d * inv + 0.5f) + one_minus_a_g);
        d = v[i].w - mn; r.w = v[i].w * (a * sigmoidf(d * d * inv + 0.5f) + one_minus_a_g);
        __builtin_nontemporal_store(r, &o4[t + 256 * i]);
    }
}

extern "C" void kernel_launch(void* const* d_in, const int* in_sizes, int n_in,
                              void* d_out, int out_size, void* d_ws, size_t ws_size,
                              hipStream_t stream) {
    const float* x      = (const float*)d_in[0];
    const float* conv_w = (const float*)d_in[1];
    const float* w1     = (const float*)d_in[2];
    const float* w2     = (const float*)d_in[3];
    float* out = (float*)d_out;

    const int BC = Bdim * Cdim;   // 8192
    float* mean_c = (float*)d_ws;            // [BC]
    float* inv_c  = mean_c + BC;             // [BC]
    float* ssum   = inv_c + BC;              // [BC]
    float* eca    = ssum + BC;               // [BC]
    float* alpha  = eca + BC;                // [BC]
    int*   cnt    = (int*)(alpha + BC);      // [Bdim]

    // counters must be zero each replay; memset node is graph-capturable
    hipMemsetAsync(cnt, 0, Bdim * sizeof(int), stream);

    stats_gate_kernel<<<BC, 256, 0, stream>>>(x, conv_w, w1, w2,
                                              mean_c, inv_c, ssum, eca, alpha, cnt);
    final_kernel<<<BC, 256, 0, stream>>>(x, mean_c, inv_c, eca, alpha, out);
}

// Round 4
// 290.449 us; speedup vs baseline: 2.0589x; 1.0728x over previous
//
#include <hip/hip_runtime.h>
#include <math.h>

#define Bdim 32
#define Cdim 256
#define Hdim 64
#define Wdim 64
#define HW   (Hdim * Wdim)          // 4096
#define KS   5
#define HID  64
#define E_LAMBDA 1e-4f

typedef float vfloat4 __attribute__((ext_vector_type(4)));

// fast sigmoid: native v_exp_f32 + v_rcp_f32 (abs err ~1e-6, threshold 8e-2)
__device__ __forceinline__ float sigmoidf(float v) {
    return __builtin_amdgcn_rcpf(1.0f + __expf(-v));
}

// ---------------- Kernel 1: per-channel stats + SimAM GAP sum -------------
// EXACT round-0 structure (259.6 us baseline): one block per (b,c) channel,
// 4096 elements in registers, one HBM read of x (warms L3 for kernel 2).
// No atomics, no fences — cross-block visibility comes from the kernel
// boundary. (Round-2 lesson: per-block agent fences collapse to 162 GB/s;
// round-3 lesson: 8192 ticket-atomics on 2 cache lines cost ~60 us of
// serialized block retirement.)
__global__ __launch_bounds__(256) void stats_kernel(
        const float* __restrict__ x,
        float* __restrict__ mean_out,
        float* __restrict__ inv_out,       // 0.25/(var+eps)
        float* __restrict__ ssum_out) {
    const int bc = blockIdx.x;
    const vfloat4* __restrict__ x4 = (const vfloat4*)(x + (size_t)bc * HW);
    const int t = threadIdx.x;

    vfloat4 v[4];
    float sum = 0.0f, sq = 0.0f;
#pragma unroll
    for (int i = 0; i < 4; ++i) {
        v[i] = x4[t + 256 * i];
        sum += v[i].x + v[i].y + v[i].z + v[i].w;
        sq  += v[i].x * v[i].x + v[i].y * v[i].y
             + v[i].z * v[i].z + v[i].w * v[i].w;
    }

#pragma unroll
    for (int off = 32; off > 0; off >>= 1) {
        sum += __shfl_down(sum, off);
        sq  += __shfl_down(sq, off);
    }

    __shared__ float red[8];
    __shared__ float bcast[2];
    const int lane = t & 63;
    const int wid  = t >> 6;
    if (lane == 0) { red[wid] = sum; red[4 + wid] = sq; }
    __syncthreads();
    if (t == 0) {
        const float ts = red[0] + red[1] + red[2] + red[3];
        const float tq = red[4] + red[5] + red[6] + red[7];
        const float mn  = ts * (1.0f / HW);
        const float var = (tq - ts * ts * (1.0f / HW)) * (1.0f / (HW - 1));
        const float iv  = 0.25f / (var + E_LAMBDA);
        mean_out[bc] = mn;
        inv_out[bc]  = iv;
        bcast[0] = mn;
        bcast[1] = iv;
    }
    __syncthreads();
    const float mn  = bcast[0];
    const float inv = bcast[1];

    // SimAM: sum over channel of x * sigmoid(d^2/(4(var+eps)) + 0.5)
    float p = 0.0f;
#pragma unroll
    for (int i = 0; i < 4; ++i) {
        float d;
        d = v[i].x - mn; p += v[i].x * sigmoidf(d * d * inv + 0.5f);
        d = v[i].y - mn; p += v[i].y * sigmoidf(d * d * inv + 0.5f);
        d = v[i].z - mn; p += v[i].z * sigmoidf(d * d * inv + 0.5f);
        d = v[i].w - mn; p += v[i].w * sigmoidf(d * d * inv + 0.5f);
    }
#pragma unroll
    for (int off = 32; off > 0; off >>= 1) p += __shfl_down(p, off);
    if (lane == 0) red[wid] = p;
    __syncthreads();
    if (t == 0) ssum_out[bc] = red[0] + red[1] + red[2] + red[3];
}

// ---------------- Kernel 2: fused gate/MLP + final blend ------------------
// Each block recomputes the ECA conv + fusion MLP for its batch from the
// 2 KB of published stats (redundant across the 256 blocks of a batch, but
// only ~33K MACs + 64 KB of L2-hot w1 reads per block — ~0.5% of device
// throughput). The 16 x-floats are loaded FIRST so their HBM/L3 latency
// hides the entire MLP. Kernel-boundary coherence only; zero atomics.
// out uses NON-TEMPORAL stores so the 128 MiB output stream doesn't evict
// x from the 256 MiB L3 (x re-read is L3-warm from kernel 1).
__global__ __launch_bounds__(256) void final_fused_kernel(
        const float* __restrict__ x,
        const float* __restrict__ mean_c,
        const float* __restrict__ inv_c,
        const float* __restrict__ ssum,
        const float* __restrict__ conv_w,
        const float* __restrict__ w1,
        const float* __restrict__ w2,
        float* __restrict__ out) {
    const int bc = blockIdx.x;
    const int b  = bc >> 8;
    const int c  = bc & (Cdim - 1);
    const int t  = threadIdx.x;

    // issue the 16 x-loads immediately; consumed only after the MLP
    const vfloat4* __restrict__ x4 = (const vfloat4*)(x + (size_t)bc * HW);
    vfloat4 v[4];
#pragma unroll
    for (int i = 0; i < 4; ++i) v[i] = x4[t + 256 * i];

    __shared__ float sm[Cdim];
    __shared__ float sgap[Cdim];
    __shared__ float sgate[Cdim];
    __shared__ float shid[HID];

    // thread t == channel t of this block's batch
    const float mb = mean_c[b * Cdim + t];
    const float sb = ssum[b * Cdim + t];
    sm[t] = mb;
    __syncthreads();

    // ECA: cross-correlation over channel dim, zero-padded by 2
    float acc = 0.0f;
#pragma unroll
    for (int k = 0; k < KS; ++k) {
        const int cc = t + k - (KS - 1) / 2;
        const float mv = (cc >= 0 && cc < Cdim) ? sm[cc] : 0.0f;
        acc += conv_w[k] * mv;
    }
    const float g_t = sigmoidf(acc);
    sgate[t] = g_t;
    // gap = mean(x_eca + x_simam) = gate*mean + ssum/HW
    sgap[t] = g_t * mb + sb * (1.0f / HW);
    __syncthreads();

    if (t < HID) {
        const vfloat4* __restrict__ w14 = (const vfloat4*)(w1 + t * Cdim);
        const vfloat4* __restrict__ g4  = (const vfloat4*)sgap;
        float h = 0.0f;
#pragma unroll
        for (int i = 0; i < Cdim / 4; ++i) {
            const vfloat4 wv = w14[i];
            const vfloat4 gv = g4[i];
            h += wv.x * gv.x + wv.y * gv.y + wv.z * gv.z + wv.w * gv.w;
        }
        shid[t] = fmaxf(h, 0.0f);
    }
    __syncthreads();

    // alpha for this block's own channel c — redundantly per thread
    // (w2 row + shid reads are uniform across the wave -> broadcast, cheap)
    float a = 0.0f;
    {
        const vfloat4* __restrict__ w24 = (const vfloat4*)(w2 + c * HID);
        const vfloat4* __restrict__ h4  = (const vfloat4*)shid;
#pragma unroll
        for (int j = 0; j < HID / 4; ++j) {
            const vfloat4 wv = w24[j];
            const vfloat4 hv = h4[j];
            a += wv.x * hv.x + wv.y * hv.y + wv.z * hv.z + wv.w * hv.w;
        }
    }
    const float alpha = sigmoidf(a);
    const float mn  = sm[c];                 // own-channel mean via LDS broadcast
    const float inv = inv_c[bc];
    const float omg = (1.0f - alpha) * sgate[c];

    vfloat4* __restrict__ o4 = (vfloat4*)(out + (size_t)bc * HW);
#pragma unroll
    for (int i = 0; i < 4; ++i) {
        vfloat4 r;
        float d;
        d = v[i].x - mn; r.x = v[i].x * (alpha * sigmoidf(d * d * inv + 0.5f) + omg);
        d = v[i].y - mn; r.y = v[i].y * (alpha * sigmoidf(d * d * inv + 0.5f) + omg);
        d = v[i].z - mn; r.z = v[i].z * (alpha * sigmoidf(d * d * inv + 0.5f) + omg);
        d = v[i].w - mn; r.w = v[i].w * (alpha * sigmoidf(d * d * inv + 0.5f) + omg);
        __builtin_nontemporal_store(r, &o4[t + 256 * i]);
    }
}

extern "C" void kernel_launch(void* const* d_in, const int* in_sizes, int n_in,
                              void* d_out, int out_size, void* d_ws, size_t ws_size,
                              hipStream_t stream) {
    const float* x      = (const float*)d_in[0];
    const float* conv_w = (const float*)d_in[1];
    const float* w1     = (const float*)d_in[2];
    const float* w2     = (const float*)d_in[3];
    float* out = (float*)d_out;

    const int BC = Bdim * Cdim;   // 8192
    float* mean_c = (float*)d_ws;            // [BC]
    float* inv_c  = mean_c + BC;             // [BC]
    float* ssum   = inv_c + BC;              // [BC]

    stats_kernel<<<BC, 256, 0, stream>>>(x, mean_c, inv_c, ssum);
    final_fused_kernel<<<BC, 256, 0, stream>>>(x, mean_c, inv_c, ssum,
                                               conv_w, w1, w2, out);
}

// Round 5
// 263.051 us; speedup vs baseline: 2.2734x; 1.1042x over previous
//
#include <hip/hip_runtime.h>
#include <math.h>

#define Bdim 32
#define Cdim 256
#define Hdim 64
#define Wdim 64
#define HW   (Hdim * Wdim)          // 4096
#define KS   5
#define HID  64
#define E_LAMBDA 1e-4f

typedef float vfloat4 __attribute__((ext_vector_type(4)));

// fast sigmoid: native v_exp_f32 + v_rcp_f32 (abs err ~1e-6, threshold 8e-2)
__device__ __forceinline__ float sigmoidf(float v) {
    return __builtin_amdgcn_rcpf(1.0f + __expf(-v));
}

// ---------------- Kernel 1: per-channel stats + SimAM GAP sum -------------
// Round-0 structure (proven): one block per (b,c) channel, 4096 elements in
// registers, one HBM read of x. Stores inv = 0.25/(var+eps) directly.
__global__ __launch_bounds__(256) void stats_kernel(
        const float* __restrict__ x,
        float* __restrict__ mean_out,
        float* __restrict__ inv_out,
        float* __restrict__ ssum_out) {
    const int bc = blockIdx.x;
    const vfloat4* __restrict__ x4 = (const vfloat4*)(x + (size_t)bc * HW);
    const int t = threadIdx.x;

    vfloat4 v[4];
    float sum = 0.0f, sq = 0.0f;
#pragma unroll
    for (int i = 0; i < 4; ++i) {
        v[i] = x4[t + 256 * i];
        sum += v[i].x + v[i].y + v[i].z + v[i].w;
        sq  += v[i].x * v[i].x + v[i].y * v[i].y
             + v[i].z * v[i].z + v[i].w * v[i].w;
    }
#pragma unroll
    for (int off = 32; off > 0; off >>= 1) {
        sum += __shfl_down(sum, off);
        sq  += __shfl_down(sq, off);
    }

    __shared__ float red[8];
    __shared__ float bcast[2];
    const int lane = t & 63;
    const int wid  = t >> 6;
    if (lane == 0) { red[wid] = sum; red[4 + wid] = sq; }
    __syncthreads();
    if (t == 0) {
        const float ts = red[0] + red[1] + red[2] + red[3];
        const float tq = red[4] + red[5] + red[6] + red[7];
        const float mn  = ts * (1.0f / HW);
        const float var = (tq - ts * ts * (1.0f / HW)) * (1.0f / (HW - 1));
        const float iv  = 0.25f / (var + E_LAMBDA);
        mean_out[bc] = mn;
        inv_out[bc]  = iv;
        bcast[0] = mn;
        bcast[1] = iv;
    }
    __syncthreads();
    const float mn  = bcast[0];
    const float inv = bcast[1];

    // SimAM: sum over channel of x * sigmoid(d^2/(4(var+eps)) + 0.5)
    float p = 0.0f;
#pragma unroll
    for (int i = 0; i < 4; ++i) {
        float d;
        d = v[i].x - mn; p += v[i].x * sigmoidf(d * d * inv + 0.5f);
        d = v[i].y - mn; p += v[i].y * sigmoidf(d * d * inv + 0.5f);
        d = v[i].z - mn; p += v[i].z * sigmoidf(d * d * inv + 0.5f);
        d = v[i].w - mn; p += v[i].w * sigmoidf(d * d * inv + 0.5f);
    }
#pragma unroll
    for (int off = 32; off > 0; off >>= 1) p += __shfl_down(p, off);
    if (lane == 0) red[wid] = p;
    __syncthreads();
    if (t == 0) ssum_out[bc] = red[0] + red[1] + red[2] + red[3];
}

// ---------------- Kernel 2: ECA conv + gap + MLP -> alpha -----------------
// One block per batch (32 blocks, 256 threads). ~8 us. Round-0 with float4 dots.
__global__ __launch_bounds__(256) void gate_mlp_kernel(
        const float* __restrict__ mean_c,
        const float* __restrict__ ssum,
        const float* __restrict__ conv_w,
        const float* __restrict__ w1,
        const float* __restrict__ w2,
        float* __restrict__ eca_out,
        float* __restrict__ alpha_out) {
    const int b = blockIdx.x;
    const int c = threadIdx.x;
    __shared__ float m[Cdim];
    __shared__ float gap[Cdim];
    __shared__ float hid[HID];

    m[c] = mean_c[b * Cdim + c];
    __syncthreads();

    float acc = 0.0f;
#pragma unroll
    for (int k = 0; k < KS; ++k) {
        const int cc = c + k - (KS - 1) / 2;
        const float mv = (cc >= 0 && cc < Cdim) ? m[cc] : 0.0f;
        acc += conv_w[k] * mv;
    }
    const float gate = sigmoidf(acc);
    eca_out[b * Cdim + c] = gate;
    gap[c] = gate * m[c] + ssum[b * Cdim + c] * (1.0f / HW);
    __syncthreads();

    if (c < HID) {
        const vfloat4* __restrict__ w14 = (const vfloat4*)(w1 + c * Cdim);
        const vfloat4* __restrict__ g4  = (const vfloat4*)gap;
        float h = 0.0f;
#pragma unroll
        for (int i = 0; i < Cdim / 4; ++i) {
            const vfloat4 wv = w14[i];
            const vfloat4 gv = g4[i];
            h += wv.x * gv.x + wv.y * gv.y + wv.z * gv.z + wv.w * gv.w;
        }
        hid[c] = fmaxf(h, 0.0f);
    }
    __syncthreads();

    float a = 0.0f;
    {
        const vfloat4* __restrict__ w24 = (const vfloat4*)(w2 + c * HID);
        const vfloat4* __restrict__ h4  = (const vfloat4*)hid;
#pragma unroll
        for (int j = 0; j < HID / 4; ++j) {
            const vfloat4 wv = w24[j];
            const vfloat4 hv = h4[j];
            a += wv.x * hv.x + wv.y * hv.y + wv.z * hv.z + wv.w * hv.w;
        }
    }
    alpha_out[b * Cdim + c] = sigmoidf(a);
}

// ---------------- Kernel 3: final elementwise blend -----------------------
// out = x * (alpha * s + (1-alpha) * gate),  s = sigmoid(d^2*inv + 0.5)
// Round-4 lesson: NT stores ran the blend at 2.4 TB/s while plain-store
// streams (fills, m13 copy) do 6.3-6.65 TB/s on this chip -> PLAIN stores.
// 2 channels / 32 floats per thread: deeper load/store pipeline per wave,
// half the block dispatches.
__global__ __launch_bounds__(256) void final_kernel(
        const float* __restrict__ x,
        const float* __restrict__ mean_c,
        const float* __restrict__ inv_c,
        const float* __restrict__ eca,
        const float* __restrict__ alpha,
        float* __restrict__ out) {
    const int bc0 = blockIdx.x * 2;          // two consecutive channels
    const int t   = threadIdx.x;

    const float mn0  = mean_c[bc0],     mn1  = mean_c[bc0 + 1];
    const float inv0 = inv_c[bc0],      inv1 = inv_c[bc0 + 1];
    const float a0   = alpha[bc0],      a1   = alpha[bc0 + 1];
    const float omg0 = (1.0f - a0) * eca[bc0];
    const float omg1 = (1.0f - a1) * eca[bc0 + 1];

    const vfloat4* __restrict__ x4 = (const vfloat4*)(x + (size_t)bc0 * HW);
    vfloat4* __restrict__ o4 = (vfloat4*)(out + (size_t)bc0 * HW);

    vfloat4 v[8];
#pragma unroll
    for (int i = 0; i < 8; ++i) v[i] = x4[t + 256 * i];

#pragma unroll
    for (int i = 0; i < 8; ++i) {
        const float mn  = (i < 4) ? mn0  : mn1;
        const float inv = (i < 4) ? inv0 : inv1;
        const float a   = (i < 4) ? a0   : a1;
        const float omg = (i < 4) ? omg0 : omg1;
        vfloat4 r;
        float d;
        d = v[i].x - mn; r.x = v[i].x * (a * sigmoidf(d * d * inv + 0.5f) + omg);
        d = v[i].y - mn; r.y = v[i].y * (a * sigmoidf(d * d * inv + 0.5f) + omg);
        d = v[i].z - mn; r.z = v[i].z * (a * sigmoidf(d * d * inv + 0.5f) + omg);
        d = v[i].w - mn; r.w = v[i].w * (a * sigmoidf(d * d * inv + 0.5f) + omg);
        o4[t + 256 * i] = r;                 // plain temporal store
    }
}

extern "C" void kernel_launch(void* const* d_in, const int* in_sizes, int n_in,
                              void* d_out, int out_size, void* d_ws, size_t ws_size,
                              hipStream_t stream) {
    const float* x      = (const float*)d_in[0];
    const float* conv_w = (const float*)d_in[1];
    const float* w1     = (const float*)d_in[2];
    const float* w2     = (const float*)d_in[3];
    float* out = (float*)d_out;

    const int BC = Bdim * Cdim;   // 8192
    float* mean_c = (float*)d_ws;            // [BC]
    float* inv_c  = mean_c + BC;             // [BC]
    float* ssum   = inv_c + BC;              // [BC]
    float* eca    = ssum + BC;               // [BC]
    float* alpha  = eca + BC;                // [BC]

    stats_kernel<<<BC, 256, 0, stream>>>(x, mean_c, inv_c, ssum);
    gate_mlp_kernel<<<Bdim, 256, 0, stream>>>(mean_c, ssum, conv_w, w1, w2, eca, alpha);
    final_kernel<<<BC / 2, 256, 0, stream>>>(x, mean_c, inv_c, eca, alpha, out);
}

// Round 6
// 262.342 us; speedup vs baseline: 2.2795x; 1.0027x over previous
//
#include <hip/hip_runtime.h>
#include <math.h>

#define Bdim 32
#define Cdim 256
#define Hdim 64
#define Wdim 64
#define HW   (Hdim * Wdim)          // 4096
#define KS   5
#define HID  64
#define E_LAMBDA 1e-4f

typedef float vfloat4 __attribute__((ext_vector_type(4)));

// fast sigmoid: native v_exp_f32 + v_rcp_f32 (abs err ~1e-6, threshold 8e-2)
__device__ __forceinline__ float sigmoidf(float v) {
    return __builtin_amdgcn_rcpf(1.0f + __expf(-v));
}

// ---------------- Kernel 1: per-channel stats + SimAM GAP sum -------------
// Proven structure: one block per (b,c) channel, 4096 elements in registers,
// one HBM read of x (leaves x resident in the 256 MB L3 for kernel 3).
__global__ __launch_bounds__(256) void stats_kernel(
        const float* __restrict__ x,
        float* __restrict__ mean_out,
        float* __restrict__ inv_out,
        float* __restrict__ ssum_out) {
    const int bc = blockIdx.x;
    const vfloat4* __restrict__ x4 = (const vfloat4*)(x + (size_t)bc * HW);
    const int t = threadIdx.x;

    vfloat4 v[4];
    float sum = 0.0f, sq = 0.0f;
#pragma unroll
    for (int i = 0; i < 4; ++i) {
        v[i] = x4[t + 256 * i];
        sum += v[i].x + v[i].y + v[i].z + v[i].w;
        sq  += v[i].x * v[i].x + v[i].y * v[i].y
             + v[i].z * v[i].z + v[i].w * v[i].w;
    }
#pragma unroll
    for (int off = 32; off > 0; off >>= 1) {
        sum += __shfl_down(sum, off);
        sq  += __shfl_down(sq, off);
    }

    __shared__ float red[8];
    __shared__ float bcast[2];
    const int lane = t & 63;
    const int wid  = t >> 6;
    if (lane == 0) { red[wid] = sum; red[4 + wid] = sq; }
    __syncthreads();
    if (t == 0) {
        const float ts = red[0] + red[1] + red[2] + red[3];
        const float tq = red[4] + red[5] + red[6] + red[7];
        const float mn  = ts * (1.0f / HW);
        const float var = (tq - ts * ts * (1.0f / HW)) * (1.0f / (HW - 1));
        const float iv  = 0.25f / (var + E_LAMBDA);
        mean_out[bc] = mn;
        inv_out[bc]  = iv;
        bcast[0] = mn;
        bcast[1] = iv;
    }
    __syncthreads();
    const float mn  = bcast[0];
    const float inv = bcast[1];

    // SimAM: sum over channel of x * sigmoid(d^2/(4(var+eps)) + 0.5)
    float p = 0.0f;
#pragma unroll
    for (int i = 0; i < 4; ++i) {
        float d;
        d = v[i].x - mn; p += v[i].x * sigmoidf(d * d * inv + 0.5f);
        d = v[i].y - mn; p += v[i].y * sigmoidf(d * d * inv + 0.5f);
        d = v[i].z - mn; p += v[i].z * sigmoidf(d * d * inv + 0.5f);
        d = v[i].w - mn; p += v[i].w * sigmoidf(d * d * inv + 0.5f);
    }
#pragma unroll
    for (int off = 32; off > 0; off >>= 1) p += __shfl_down(p, off);
    if (lane == 0) red[wid] = p;
    __syncthreads();
    if (t == 0) ssum_out[bc] = red[0] + red[1] + red[2] + red[3];
}

// ---------------- Kernel 2: ECA conv + gap + MLP -> alpha -----------------
// One block per batch (32 blocks, 256 threads). ~8 us, latency-bound.
__global__ __launch_bounds__(256) void gate_mlp_kernel(
        const float* __restrict__ mean_c,
        const float* __restrict__ ssum,
        const float* __restrict__ conv_w,
        const float* __restrict__ w1,
        const float* __restrict__ w2,
        float* __restrict__ eca_out,
        float* __restrict__ alpha_out) {
    const int b = blockIdx.x;
    const int c = threadIdx.x;
    __shared__ float m[Cdim];
    __shared__ float gap[Cdim];
    __shared__ float hid[HID];

    m[c] = mean_c[b * Cdim + c];
    __syncthreads();

    float acc = 0.0f;
#pragma unroll
    for (int k = 0; k < KS; ++k) {
        const int cc = c + k - (KS - 1) / 2;
        const float mv = (cc >= 0 && cc < Cdim) ? m[cc] : 0.0f;
        acc += conv_w[k] * mv;
    }
    const float gate = sigmoidf(acc);
    eca_out[b * Cdim + c] = gate;
    gap[c] = gate * m[c] + ssum[b * Cdim + c] * (1.0f / HW);
    __syncthreads();

    if (c < HID) {
        const vfloat4* __restrict__ w14 = (const vfloat4*)(w1 + c * Cdim);
        const vfloat4* __restrict__ g4  = (const vfloat4*)gap;
        float h = 0.0f;
#pragma unroll
        for (int i = 0; i < Cdim / 4; ++i) {
            const vfloat4 wv = w14[i];
            const vfloat4 gv = g4[i];
            h += wv.x * gv.x + wv.y * gv.y + wv.z * gv.z + wv.w * gv.w;
        }
        hid[c] = fmaxf(h, 0.0f);
    }
    __syncthreads();

    float a = 0.0f;
    {
        const vfloat4* __restrict__ w24 = (const vfloat4*)(w2 + c * HID);
        const vfloat4* __restrict__ h4  = (const vfloat4*)hid;
#pragma unroll
        for (int j = 0; j < HID / 4; ++j) {
            const vfloat4 wv = w24[j];
            const vfloat4 hv = h4[j];
            a += wv.x * hv.x + wv.y * hv.y + wv.z * hv.z + wv.w * hv.w;
        }
    }
    alpha_out[b * Cdim + c] = sigmoidf(a);
}

// ---------------- Kernel 3: final elementwise blend -----------------------
// out = x * (alpha * s + (1-alpha) * gate),  s = sigmoid(d^2*inv + 0.5)
//
// NT stores are deliberate and load-bearing: x (134 MB) is fully L3-resident
// after kernel 1; a plain-store out stream write-allocates 134 MB in L3 and
// evicts ~half of x before it is read (round-4 counters: FETCH ~= x/2). NT
// stores bypass L3 allocation -> x reads stay L3 hits, writes stream to HBM.
// (Round-4's "NT is slow" reading was confounded by the fused MLP; round-0
// NT pure-stream beat round-5 plain pure-stream.)
// 2 channels / 32 floats per thread: 16 outstanding float4 loads per thread,
// half the dispatches vs 1ch/block.
__global__ __launch_bounds__(256) void final_kernel(
        const float* __restrict__ x,
        const float* __restrict__ mean_c,
        const float* __restrict__ inv_c,
        const float* __restrict__ eca,
        const float* __restrict__ alpha,
        float* __restrict__ out) {
    const int bc0 = blockIdx.x * 2;          // two consecutive channels
    const int t   = threadIdx.x;

    const float mn0  = mean_c[bc0],     mn1  = mean_c[bc0 + 1];
    const float inv0 = inv_c[bc0],      inv1 = inv_c[bc0 + 1];
    const float a0   = alpha[bc0],      a1   = alpha[bc0 + 1];
    const float omg0 = (1.0f - a0) * eca[bc0];
    const float omg1 = (1.0f - a1) * eca[bc0 + 1];

    const vfloat4* __restrict__ x4 = (const vfloat4*)(x + (size_t)bc0 * HW);
    vfloat4* __restrict__ o4 = (vfloat4*)(out + (size_t)bc0 * HW);

    vfloat4 v[8];
#pragma unroll
    for (int i = 0; i < 8; ++i) v[i] = x4[t + 256 * i];

#pragma unroll
    for (int i = 0; i < 8; ++i) {
        const float mn  = (i < 4) ? mn0  : mn1;
        const float inv = (i < 4) ? inv0 : inv1;
        const float a   = (i < 4) ? a0   : a1;
        const float omg = (i < 4) ? omg0 : omg1;
        vfloat4 r;
        float d;
        d = v[i].x - mn; r.x = v[i].x * (a * sigmoidf(d * d * inv + 0.5f) + omg);
        d = v[i].y - mn; r.y = v[i].y * (a * sigmoidf(d * d * inv + 0.5f) + omg);
        d = v[i].z - mn; r.z = v[i].z * (a * sigmoidf(d * d * inv + 0.5f) + omg);
        d = v[i].w - mn; r.w = v[i].w * (a * sigmoidf(d * d * inv + 0.5f) + omg);
        __builtin_nontemporal_store(r, &o4[t + 256 * i]);
    }
}

extern "C" void kernel_launch(void* const* d_in, const int* in_sizes, int n_in,
                              void* d_out, int out_size, void* d_ws, size_t ws_size,
                              hipStream_t stream) {
    const float* x      = (const float*)d_in[0];
    const float* conv_w = (const float*)d_in[1];
    const float* w1     = (const float*)d_in[2];
    const float* w2     = (const float*)d_in[3];
    float* out = (float*)d_out;

    const int BC = Bdim * Cdim;   // 8192
    float* mean_c = (float*)d_ws;            // [BC]
    float* inv_c  = mean_c + BC;             // [BC]
    float* ssum   = inv_c + BC;              // [BC]
    float* eca    = ssum + BC;               // [BC]
    float* alpha  = eca + BC;                // [BC]

    stats_kernel<<<BC, 256, 0, stream>>>(x, mean_c, inv_c, ssum);
    gate_mlp_kernel<<<Bdim, 256, 0, stream>>>(mean_c, ssum, conv_w, w1, w2, eca, alpha);
    final_kernel<<<BC / 2, 256, 0, stream>>>(x, mean_c, inv_c, eca, alpha, out);
}

// Round 7
// 261.631 us; speedup vs baseline: 2.2857x; 1.0027x over previous
//
#include <hip/hip_runtime.h>
#include <math.h>

#define Bdim 32
#define Cdim 256
#define Hdim 64
#define Wdim 64
#define HW   (Hdim * Wdim)          // 4096
#define KS   5
#define HID  64
#define E_LAMBDA 1e-4f

typedef float vfloat4 __attribute__((ext_vector_type(4)));

// fast sigmoid: native v_exp_f32 + v_rcp_f32 (abs err ~1e-6, threshold 8e-2)
__device__ __forceinline__ float sigmoidf(float v) {
    return __builtin_amdgcn_rcpf(1.0f + __expf(-v));
}

// ---------------- Kernel 1: per-channel stats + SimAM GAP sum -------------
// One block per (b,c) channel. 256 threads x 16 floats = 4096 elements held
// in registers; one HBM read of x total (also warms L3 for kernel 3).
// Proven round-0 structure; stores inv = 0.25/(var+eps) directly (saves a
// divide in every final block).
__global__ __launch_bounds__(256) void stats_kernel(
        const float* __restrict__ x,
        float* __restrict__ mean_out,
        float* __restrict__ inv_out,
        float* __restrict__ ssum_out) {
    const int bc = blockIdx.x;
    const vfloat4* __restrict__ x4 = (const vfloat4*)(x + (size_t)bc * HW);
    const int t = threadIdx.x;

    vfloat4 v[4];
    float sum = 0.0f, sq = 0.0f;
#pragma unroll
    for (int i = 0; i < 4; ++i) {
        v[i] = x4[t + 256 * i];
        sum += v[i].x + v[i].y + v[i].z + v[i].w;
        sq  += v[i].x * v[i].x + v[i].y * v[i].y
             + v[i].z * v[i].z + v[i].w * v[i].w;
    }

    // wave (64-lane) butterfly reduction of both accumulators
#pragma unroll
    for (int off = 32; off > 0; off >>= 1) {
        sum += __shfl_down(sum, off);
        sq  += __shfl_down(sq, off);
    }

    __shared__ float red[8];
    __shared__ float bcast[2];
    const int lane = t & 63;
    const int wid  = t >> 6;
    if (lane == 0) { red[wid] = sum; red[4 + wid] = sq; }
    __syncthreads();
    if (t == 0) {
        const float ts = red[0] + red[1] + red[2] + red[3];
        const float tq = red[4] + red[5] + red[6] + red[7];
        const float mn  = ts * (1.0f / HW);
        const float var = (tq - ts * ts * (1.0f / HW)) * (1.0f / (HW - 1));
        const float iv  = 0.25f / (var + E_LAMBDA);
        mean_out[bc] = mn;
        inv_out[bc]  = iv;
        bcast[0] = mn;
        bcast[1] = iv;
    }
    __syncthreads();
    const float mn  = bcast[0];
    const float inv = bcast[1];

    // SimAM: sum over channel of x * sigmoid(d^2/(4(var+eps)) + 0.5)
    float p = 0.0f;
#pragma unroll
    for (int i = 0; i < 4; ++i) {
        float d;
        d = v[i].x - mn; p += v[i].x * sigmoidf(d * d * inv + 0.5f);
        d = v[i].y - mn; p += v[i].y * sigmoidf(d * d * inv + 0.5f);
        d = v[i].z - mn; p += v[i].z * sigmoidf(d * d * inv + 0.5f);
        d = v[i].w - mn; p += v[i].w * sigmoidf(d * d * inv + 0.5f);
    }
#pragma unroll
    for (int off = 32; off > 0; off >>= 1) p += __shfl_down(p, off);
    if (lane == 0) red[wid] = p;
    __syncthreads();
    if (t == 0) ssum_out[bc] = red[0] + red[1] + red[2] + red[3];
}

// ---------------- Kernel 2: ECA conv + gap + MLP -> alpha -----------------
// One block per batch (32 blocks, 256 threads). Latency-bound, ~8 us.
__global__ __launch_bounds__(256) void gate_mlp_kernel(
        const float* __restrict__ mean_c,
        const float* __restrict__ ssum,
        const float* __restrict__ conv_w,
        const float* __restrict__ w1,
        const float* __restrict__ w2,
        float* __restrict__ eca_out,
        float* __restrict__ alpha_out) {
    const int b = blockIdx.x;
    const int c = threadIdx.x;
    __shared__ float m[Cdim];
    __shared__ float gap[Cdim];
    __shared__ float hid[HID];

    m[c] = mean_c[b * Cdim + c];
    __syncthreads();

    // ECA: cross-correlation over channel dim, zero-padded by 2
    float acc = 0.0f;
#pragma unroll
    for (int k = 0; k < KS; ++k) {
        const int cc = c + k - (KS - 1) / 2;
        const float mv = (cc >= 0 && cc < Cdim) ? m[cc] : 0.0f;
        acc += conv_w[k] * mv;
    }
    const float gate = sigmoidf(acc);
    eca_out[b * Cdim + c] = gate;
    // gap = mean(x_eca + x_simam) = gate*mean + ssum/HW
    gap[c] = gate * m[c] + ssum[b * Cdim + c] * (1.0f / HW);
    __syncthreads();

    if (c < HID) {
        const vfloat4* __restrict__ w14 = (const vfloat4*)(w1 + c * Cdim);
        const vfloat4* __restrict__ g4  = (const vfloat4*)gap;
        float h = 0.0f;
#pragma unroll
        for (int i = 0; i < Cdim / 4; ++i) {
            const vfloat4 wv = w14[i];
            const vfloat4 gv = g4[i];
            h += wv.x * gv.x + wv.y * gv.y + wv.z * gv.z + wv.w * gv.w;
        }
        hid[c] = fmaxf(h, 0.0f);
    }
    __syncthreads();

    float a = 0.0f;
    {
        const vfloat4* __restrict__ w24 = (const vfloat4*)(w2 + c * HID);
        const vfloat4* __restrict__ h4  = (const vfloat4*)hid;
#pragma unroll
        for (int j = 0; j < HID / 4; ++j) {
            const vfloat4 wv = w24[j];
            const vfloat4 hv = h4[j];
            a += wv.x * hv.x + wv.y * hv.y + wv.z * hv.z + wv.w * hv.w;
        }
    }
    alpha_out[b * Cdim + c] = sigmoidf(a);
}

// ---------------- Kernel 3: final elementwise blend -----------------------
// out = x * (alpha * s + (1-alpha) * gate),  s = sigmoid(d^2*inv + 0.5)
// EXACT round-0 shape (best measured: 259.6 us): 1 channel per block, NT
// stores. Measured alternatives: plain stores +3.5 us, 2ch/block +2.7 us
// (VGPR/tail effects), fused MLP +31 us, sync-based single-pass +52..+338 us.
__global__ __launch_bounds__(256) void final_kernel(
        const float* __restrict__ x,
        const float* __restrict__ mean_c,
        const float* __restrict__ inv_c,
        const float* __restrict__ eca,
        const float* __restrict__ alpha,
        float* __restrict__ out) {
    const int bc = blockIdx.x;
    const float mn  = mean_c[bc];
    const float inv = inv_c[bc];
    const float g   = eca[bc];
    const float a   = alpha[bc];
    const float one_minus_a_g = (1.0f - a) * g;

    const vfloat4* __restrict__ x4 = (const vfloat4*)(x + (size_t)bc * HW);
    vfloat4* __restrict__ o4 = (vfloat4*)(out + (size_t)bc * HW);
    const int t = threadIdx.x;

#pragma unroll
    for (int i = 0; i < 4; ++i) {
        const vfloat4 v = x4[t + 256 * i];
        vfloat4 r;
        float d;
        d = v.x - mn; r.x = v.x * (a * sigmoidf(d * d * inv + 0.5f) + one_minus_a_g);
        d = v.y - mn; r.y = v.y * (a * sigmoidf(d * d * inv + 0.5f) + one_minus_a_g);
        d = v.z - mn; r.z = v.z * (a * sigmoidf(d * d * inv + 0.5f) + one_minus_a_g);
        d = v.w - mn; r.w = v.w * (a * sigmoidf(d * d * inv + 0.5f) + one_minus_a_g);
        __builtin_nontemporal_store(r, &o4[t + 256 * i]);
    }
}

extern "C" void kernel_launch(void* const* d_in, const int* in_sizes, int n_in,
                              void* d_out, int out_size, void* d_ws, size_t ws_size,
                              hipStream_t stream) {
    const float* x      = (const float*)d_in[0];
    const float* conv_w = (const float*)d_in[1];
    const float* w1     = (const float*)d_in[2];
    const float* w2     = (const float*)d_in[3];
    float* out = (float*)d_out;

    const int BC = Bdim * Cdim;   // 8192
    float* mean_c = (float*)d_ws;            // [BC]
    float* inv_c  = mean_c + BC;             // [BC]
    float* ssum   = inv_c + BC;              // [BC]
    float* eca    = ssum + BC;               // [BC]
    float* alpha  = eca + BC;                // [BC]

    stats_kernel<<<BC, 256, 0, stream>>>(x, mean_c, inv_c, ssum);
    gate_mlp_kernel<<<Bdim, 256, 0, stream>>>(mean_c, ssum, conv_w, w1, w2, eca, alpha);
    final_kernel<<<BC, 256, 0, stream>>>(x, mean_c, inv_c, eca, alpha, out);
}